// Round 4
// baseline (467.143 us; speedup 1.0000x reference)
//
#include <hip/hip_runtime.h>
#include <hip/hip_bf16.h>
#include <cstdint>
#include <cstddef>

#define N_NODES 100000
#define N_EDGES 1600000
#define F_IN 256
#define F_OUT 128

#define NB 782        // buckets = row >> 7 (128 rows each)
#define NBLK 196      // tiles for bucket_hist/scatter
#define TILE 8192     // edges per tile
#define CAP 4096      // max edges staged per bucket (mean 2048, sigma 45)

typedef __attribute__((ext_vector_type(8))) short short8;
typedef __attribute__((ext_vector_type(4))) float floatx4;

static __device__ __forceinline__ unsigned short f2bf(float f) {
    union { float f; unsigned u; } v; v.f = f;
    unsigned r = v.u + 0x7FFF + ((v.u >> 16) & 1);   // RNE
    return (unsigned short)(r >> 16);
}

// ---- w prep: fp32 [K=256][N=128] -> bf16 swizzled wT layout -----------------
__global__ void prep_w(const float* __restrict__ w, unsigned short* __restrict__ wT) {
    int i = blockIdx.x * 256 + threadIdx.x;   // 0..32767
    int k = i >> 7;
    int n = i & 127;
    int g = (k >> 3) ^ (n & 7);
    wT[n * 256 + g * 8 + (k & 7)] = f2bf(w[i]);
}

// ---- GEMM: h[100000][128] (bf16, channel-permuted) = x (fp32) @ w ----------
// h row layout: position p holds channel (p&7)*16 + (p>>3). Lane l16's 16B
// load (positions 8*l16..8*l16+7) then carries channels {j*16+l16, j=0..7}.
// This makes the GEMM epilogue a single packed short8 store per (mf,reg)
// (256 B/instr coalesced) instead of 8 scalar 2-B stores.
__global__ __launch_bounds__(256, 2) void gemm_xw(const float* __restrict__ x,
                                                  const unsigned short* __restrict__ wT,
                                                  unsigned short* __restrict__ h) {
    __shared__ __align__(16) unsigned short wlds[128 * 256];   // 64 KB
    const int tid = threadIdx.x;
    {
        const floatx4* src = reinterpret_cast<const floatx4*>(wT);
        floatx4* dst = reinterpret_cast<floatx4*>(wlds);
        #pragma unroll
        for (int i = 0; i < 16; i++) dst[tid + i * 256] = src[tid + i * 256];
    }
    __syncthreads();

    const int wave = tid >> 6, lane = tid & 63;
    const int quad = lane >> 4, l16 = lane & 15;
    const int rowbase = blockIdx.x * 256 + wave * 64;

    floatx4 acc[4][8];
    #pragma unroll
    for (int mf = 0; mf < 4; mf++)
        #pragma unroll
        for (int nt = 0; nt < 8; nt++) acc[mf][nt] = (floatx4)0.f;

    #pragma unroll
    for (int ks = 0; ks < 8; ks++) {
        const int k0 = ks * 32 + quad * 8;
        short8 afrag[4];
        #pragma unroll
        for (int mf = 0; mf < 4; mf++) {
            int row = rowbase + mf * 16 + l16;
            if (row >= N_NODES) row = N_NODES - 1;
            const float* xp = x + (size_t)row * F_IN + k0;
            floatx4 x0 = *reinterpret_cast<const floatx4*>(xp);
            floatx4 x1 = *reinterpret_cast<const floatx4*>(xp + 4);
            short8 a;
            a[0] = (short)f2bf(x0[0]); a[1] = (short)f2bf(x0[1]);
            a[2] = (short)f2bf(x0[2]); a[3] = (short)f2bf(x0[3]);
            a[4] = (short)f2bf(x1[0]); a[5] = (short)f2bf(x1[1]);
            a[6] = (short)f2bf(x1[2]); a[7] = (short)f2bf(x1[3]);
            afrag[mf] = a;
        }
        short8 bfrag[8];
        const int gq = ks * 4 + quad;
        #pragma unroll
        for (int nt = 0; nt < 8; nt++) {
            const int n = nt * 16 + l16;
            const int g = gq ^ (n & 7);
            bfrag[nt] = *reinterpret_cast<const short8*>(&wlds[n * 256 + g * 8]);
        }
        #pragma unroll
        for (int mf = 0; mf < 4; mf++)
            #pragma unroll
            for (int nt = 0; nt < 8; nt++)
                acc[mf][nt] = __builtin_amdgcn_mfma_f32_16x16x32_bf16(
                    afrag[mf], bfrag[nt], acc[mf][nt], 0, 0, 0);
    }

    #pragma unroll
    for (int mf = 0; mf < 4; mf++) {
        const int mbase = rowbase + mf * 16 + quad * 4;
        #pragma unroll
        for (int reg = 0; reg < 4; reg++) {
            const int m = mbase + reg;
            if (m < N_NODES) {
                short8 hv;
                #pragma unroll
                for (int nt = 0; nt < 8; nt++) hv[nt] = (short)f2bf(acc[mf][nt][reg]);
                *reinterpret_cast<short8*>(&h[(size_t)m * F_OUT + l16 * 8]) = hv;
            }
        }
    }
}

// ---- bucket build: group edges by 128-row bucket (rl tag in bits 24-31) ----
__global__ __launch_bounds__(256) void bucket_hist(const int* __restrict__ row,
                                                   int* __restrict__ bucket_total,
                                                   int* __restrict__ blockbase) {
    __shared__ int hist[NB];
    const int t = threadIdx.x, blk = blockIdx.x;
    for (int i = t; i < NB; i += 256) hist[i] = 0;
    __syncthreads();
    const long tb = (long)blk * TILE;
    #pragma unroll
    for (int c = 0; c < 8; c++) {
        long i0 = tb + c * 1024 + t * 4;
        if (i0 + 4 <= N_EDGES) {
            int4 r = *reinterpret_cast<const int4*>(row + i0);
            atomicAdd(&hist[r.x >> 7], 1); atomicAdd(&hist[r.y >> 7], 1);
            atomicAdd(&hist[r.z >> 7], 1); atomicAdd(&hist[r.w >> 7], 1);
        } else {
            for (long i = i0; i < N_EDGES && i < i0 + 4; i++)
                atomicAdd(&hist[row[i] >> 7], 1);
        }
    }
    __syncthreads();
    for (int bin = t; bin < NB; bin += 256)
        blockbase[bin * NBLK + blk] = atomicAdd(&bucket_total[bin], hist[bin]);
}

// exclusive scan over NB bucket totals: single wave, shfl-based, no barriers
__global__ void bucket_scan(const int* __restrict__ bucket_total,
                            int* __restrict__ bucket_base) {
    const int lane = threadIdx.x;          // 64 threads = 1 wave
    int loc[13];
    int s = 0;
    #pragma unroll
    for (int k = 0; k < 13; k++) {
        int idx = lane * 13 + k;           // 64*13 = 832 >= NB+1
        int v = (idx < NB) ? bucket_total[idx] : 0;
        loc[k] = s; s += v;                // exclusive within chunk
    }
    int run = s;
    #pragma unroll
    for (int off = 1; off < 64; off <<= 1) {
        int u = __shfl_up(run, off);
        if (lane >= off) run += u;
    }
    const int base = run - s;              // exclusive prefix of this chunk
    #pragma unroll
    for (int k = 0; k < 13; k++) {
        int idx = lane * 13 + k;
        if (idx <= NB) bucket_base[idx] = base + loc[k];
    }
}

// scatter edges to bucket-grouped metabuf; rank via LDS cursor (no G atomics)
__global__ __launch_bounds__(256) void bucket_scatter(const int* __restrict__ row,
                                                      const int* __restrict__ col,
                                                      const float* __restrict__ val,
                                                      const int* __restrict__ bucket_base,
                                                      const int* __restrict__ blockbase,
                                                      int2* __restrict__ metabuf) {
    __shared__ int sbase[NB];
    const int t = threadIdx.x, blk = blockIdx.x;
    for (int bin = t; bin < NB; bin += 256)
        sbase[bin] = bucket_base[bin] + blockbase[bin * NBLK + blk];
    __syncthreads();
    const long tb = (long)blk * TILE;
    #pragma unroll
    for (int c = 0; c < 8; c++) {
        long i0 = tb + c * 1024 + t * 4;
        if (i0 + 4 <= N_EDGES) {
            int4 r  = *reinterpret_cast<const int4*>(row + i0);
            int4 cc = *reinterpret_cast<const int4*>(col + i0);
            floatx4 vv = *reinterpret_cast<const floatx4*>(val + i0);
            int rr[4] = {r.x, r.y, r.z, r.w};
            int c4[4] = {cc.x, cc.y, cc.z, cc.w};
            float v4[4] = {vv[0], vv[1], vv[2], vv[3]};
            #pragma unroll
            for (int j = 0; j < 4; j++) {
                int bin = rr[j] >> 7, rl = rr[j] & 127;
                int pos = atomicAdd(&sbase[bin], 1);
                metabuf[pos] = make_int2(c4[j] | (rl << 24), __float_as_int(v4[j]));
            }
        } else {
            for (long i = i0; i < N_EDGES && i < i0 + 4; i++) {
                int rv = row[i];
                int bin = rv >> 7, rl = rv & 127;
                int pos = atomicAdd(&sbase[bin], 1);
                metabuf[pos] = make_int2(col[i] | (rl << 24), __float_as_int(val[i]));
            }
        }
    }
}

// ---- SpMM fused with in-LDS binning: one block per 128-row bucket ----------
// Phase 1: LDS int-atomic hist + single-wave shfl scan (2 barriers, was ~17)
//          + permute edges into LDS st[] in row order.
// Phase 2: 32 groups x 16 lanes; group owns 4 rows; 4 edges in flight with
//          depth-2 software pipeline (next 4 h-row gathers issued before the
//          FMA block consumes the current 4). Lane's acc[j] = channel
//          j*16+l16 (h is channel-permuted); out written as 8x 64-B stores.
__global__ __launch_bounds__(512, 8) void spmm_fused(const unsigned short* __restrict__ h,
                                                     const int* __restrict__ bucket_base,
                                                     const int2* __restrict__ meta,
                                                     const float* __restrict__ bias,
                                                     float* __restrict__ out) {
    __shared__ int2 st[CAP];                       // 32 KB
    __shared__ int hist[128], startS[128], cursor[128];
    const int t = threadIdx.x, b = blockIdx.x;
    const int b0 = bucket_base[b];
    int n = bucket_base[b + 1] - b0; if (n > CAP) n = CAP;

    if (t < 128) hist[t] = 0;
    __syncthreads();
    // pass 1: row-local histogram (meta region is L2-hot after scatter)
    for (int i = t; i < n; i += 512)
        atomicAdd(&hist[((unsigned)meta[b0 + i].x >> 24) & 127], 1);
    __syncthreads();
    // single-wave exclusive scan over 128 bins (2 per lane)
    if (t < 64) {
        int h0 = hist[t], h1 = hist[t + 64];
        int s0 = h0, s1 = h1;
        #pragma unroll
        for (int off = 1; off < 64; off <<= 1) {
            int u0 = __shfl_up(s0, off);
            int u1 = __shfl_up(s1, off);
            if (t >= off) { s0 += u0; s1 += u1; }
        }
        s1 += __shfl(s0, 63);
        startS[t] = s0 - h0;      cursor[t] = s0 - h0;
        startS[t + 64] = s1 - h1; cursor[t + 64] = s1 - h1;
    }
    __syncthreads();
    // pass 2: permute into st (strip rl tag from col)
    for (int i = t; i < n; i += 512) {
        int2 e = meta[b0 + i];
        int rl = ((unsigned)e.x >> 24) & 127;
        int pos = atomicAdd(&cursor[rl], 1);
        st[pos] = make_int2(e.x & 0x00FFFFFF, e.y);
    }
    __syncthreads();

    // phase 2: register accumulation over row runs, depth-2 gather pipeline
    const int lane = t & 63;
    const int l16 = lane & 15;
    const int grp = (t >> 6) * 4 + (lane >> 4);    // 0..31
    const unsigned short* hp = h + l16 * 8;

    #pragma unroll
    for (int j = 0; j < 4; j++) {
        const int rl = grp * 4 + j;
        const int s = startS[rl], d = hist[rl];
        float acc[8];
        #pragma unroll
        for (int k = 0; k < 8; k++) acc[k] = 0.f;
        if (d > 0) {
            int2 mmc[4];
            uint4 hvc[4];
            #pragma unroll
            for (int u = 0; u < 4; u++) { int idx = (u < d) ? u : d - 1; mmc[u] = st[s + idx]; }
            #pragma unroll
            for (int u = 0; u < 4; u++)
                hvc[u] = *reinterpret_cast<const uint4*>(hp + (size_t)mmc[u].x * F_OUT);
            for (int i = 0; i < d; i += 4) {
                int2 mmn[4];
                uint4 hvn[4];
                const bool more = (i + 4) < d;
                if (more) {
                    #pragma unroll
                    for (int u = 0; u < 4; u++) {
                        int idx = i + 4 + u; if (idx > d - 1) idx = d - 1;
                        mmn[u] = st[s + idx];
                    }
                    #pragma unroll
                    for (int u = 0; u < 4; u++)
                        hvn[u] = *reinterpret_cast<const uint4*>(hp + (size_t)mmn[u].x * F_OUT);
                }
                #pragma unroll
                for (int u = 0; u < 4; u++) {
                    float v = (i + u < d) ? __int_as_float(mmc[u].y) : 0.f;
                    #pragma unroll
                    for (int k = 0; k < 4; k++) {
                        unsigned uu = ((const unsigned*)&hvc[u])[k];
                        acc[2 * k]     += v * __uint_as_float(uu << 16);
                        acc[2 * k + 1] += v * __uint_as_float(uu & 0xffff0000u);
                    }
                }
                if (more) {
                    #pragma unroll
                    for (int u = 0; u < 4; u++) { mmc[u] = mmn[u]; hvc[u] = hvn[u]; }
                }
            }
        }
        const int r = b * 128 + rl;
        if (r < N_NODES) {
            float* op = out + (size_t)r * F_OUT + l16;
            #pragma unroll
            for (int jc = 0; jc < 8; jc++) {
                float o = fmaxf(acc[jc] + bias[jc * 16 + l16], 0.f);
                op[jc * 16] = o;                   // 16 lanes x 4 B = 64 B/instr
            }
        }
    }
}

extern "C" void kernel_launch(void* const* d_in, const int* in_sizes, int n_in,
                              void* d_out, int out_size, void* d_ws, size_t ws_size,
                              hipStream_t stream) {
    const float* x        = (const float*)d_in[0];
    const int*   adj_row  = (const int*)d_in[1];
    const int*   adj_col  = (const int*)d_in[2];
    const float* adj_vals = (const float*)d_in[3];
    const float* w        = (const float*)d_in[4];
    const float* b        = (const float*)d_in[5];
    float* out = (float*)d_out;

    // workspace layout (16B-aligned)
    char* ws = (char*)d_ws;
    unsigned short* wT = (unsigned short*)ws;                          // 64 KB
    unsigned short* h  = (unsigned short*)(ws + 65536);                // 25.6 MB
    size_t off = 65536 + (size_t)N_NODES * F_OUT * 2;                  // 25,665,536
    int2* metabuf  = (int2*)(ws + off);   off += (size_t)N_EDGES * 8;  // 12.8 MB
    int* blockbase = (int*)(ws + off);    off += (size_t)NB * NBLK * 4;
    int* bucket_total = (int*)(ws + off); off += 3136;
    int* bucket_base  = (int*)(ws + off); off += 3136;

    prep_w<<<128, 256, 0, stream>>>(w, wT);
    hipMemsetAsync(bucket_total, 0, NB * 4, stream);
    gemm_xw<<<(N_NODES + 255) / 256, 256, 0, stream>>>(x, wT, h);
    bucket_hist<<<NBLK, 256, 0, stream>>>(adj_row, bucket_total, blockbase);
    bucket_scan<<<1, 64, 0, stream>>>(bucket_total, bucket_base);
    bucket_scatter<<<NBLK, 256, 0, stream>>>(adj_row, adj_col, adj_vals,
                                             bucket_base, blockbase, metabuf);
    spmm_fused<<<NB, 512, 0, stream>>>(h, bucket_base, metabuf, b, out);
}

// Round 5
// 304.277 us; speedup vs baseline: 1.5353x; 1.5353x over previous
//
#include <hip/hip_runtime.h>
#include <hip/hip_bf16.h>
#include <cstdint>
#include <cstddef>

#define N_NODES 100000
#define N_EDGES 1600000
#define F_IN 256
#define F_OUT 128

#define NB 1563       // buckets = row >> 6 (64 rows each); 99999>>6 = 1562
#define NBLK 196      // tiles for bucket_hist/scatter
#define TILE 8192     // edges per tile
#define CAP 1536      // max edges staged per bucket (mean 1024, sigma 32 -> +16s)

typedef __attribute__((ext_vector_type(8))) short short8;
typedef __attribute__((ext_vector_type(4))) float floatx4;

static __device__ __forceinline__ unsigned short f2bf(float f) {
    union { float f; unsigned u; } v; v.f = f;
    unsigned r = v.u + 0x7FFF + ((v.u >> 16) & 1);   // RNE
    return (unsigned short)(r >> 16);
}

// ---- w prep: fp32 [K=256][N=128] -> bf16 swizzled wT layout -----------------
__global__ void prep_w(const float* __restrict__ w, unsigned short* __restrict__ wT) {
    int i = blockIdx.x * 256 + threadIdx.x;   // 0..32767
    int k = i >> 7;
    int n = i & 127;
    int g = (k >> 3) ^ (n & 7);
    wT[n * 256 + g * 8 + (k & 7)] = f2bf(w[i]);
}

// ---- GEMM: h[100000][128] (bf16, channel-permuted) = x (fp32) @ w ----------
// h row layout: position p holds channel (p&7)*16 + (p>>3). Lane l16's 16B
// load (positions 8*l16..8*l16+7) then carries channels {j*16+l16, j=0..7}.
// Validated end-to-end in round 4 (absmax 0.125 pass).
__global__ __launch_bounds__(256, 2) void gemm_xw(const float* __restrict__ x,
                                                  const unsigned short* __restrict__ wT,
                                                  unsigned short* __restrict__ h) {
    __shared__ __align__(16) unsigned short wlds[128 * 256];   // 64 KB
    const int tid = threadIdx.x;
    {
        const floatx4* src = reinterpret_cast<const floatx4*>(wT);
        floatx4* dst = reinterpret_cast<floatx4*>(wlds);
        #pragma unroll
        for (int i = 0; i < 16; i++) dst[tid + i * 256] = src[tid + i * 256];
    }
    __syncthreads();

    const int wave = tid >> 6, lane = tid & 63;
    const int quad = lane >> 4, l16 = lane & 15;
    const int rowbase = blockIdx.x * 256 + wave * 64;

    floatx4 acc[4][8];
    #pragma unroll
    for (int mf = 0; mf < 4; mf++)
        #pragma unroll
        for (int nt = 0; nt < 8; nt++) acc[mf][nt] = (floatx4)0.f;

    #pragma unroll
    for (int ks = 0; ks < 8; ks++) {
        const int k0 = ks * 32 + quad * 8;
        short8 afrag[4];
        #pragma unroll
        for (int mf = 0; mf < 4; mf++) {
            int row = rowbase + mf * 16 + l16;
            if (row >= N_NODES) row = N_NODES - 1;
            const float* xp = x + (size_t)row * F_IN + k0;
            floatx4 x0 = *reinterpret_cast<const floatx4*>(xp);
            floatx4 x1 = *reinterpret_cast<const floatx4*>(xp + 4);
            short8 a;
            a[0] = (short)f2bf(x0[0]); a[1] = (short)f2bf(x0[1]);
            a[2] = (short)f2bf(x0[2]); a[3] = (short)f2bf(x0[3]);
            a[4] = (short)f2bf(x1[0]); a[5] = (short)f2bf(x1[1]);
            a[6] = (short)f2bf(x1[2]); a[7] = (short)f2bf(x1[3]);
            afrag[mf] = a;
        }
        short8 bfrag[8];
        const int gq = ks * 4 + quad;
        #pragma unroll
        for (int nt = 0; nt < 8; nt++) {
            const int n = nt * 16 + l16;
            const int g = gq ^ (n & 7);
            bfrag[nt] = *reinterpret_cast<const short8*>(&wlds[n * 256 + g * 8]);
        }
        #pragma unroll
        for (int mf = 0; mf < 4; mf++)
            #pragma unroll
            for (int nt = 0; nt < 8; nt++)
                acc[mf][nt] = __builtin_amdgcn_mfma_f32_16x16x32_bf16(
                    afrag[mf], bfrag[nt], acc[mf][nt], 0, 0, 0);
    }

    #pragma unroll
    for (int mf = 0; mf < 4; mf++) {
        const int mbase = rowbase + mf * 16 + quad * 4;
        #pragma unroll
        for (int reg = 0; reg < 4; reg++) {
            const int m = mbase + reg;
            if (m < N_NODES) {
                short8 hv;
                #pragma unroll
                for (int nt = 0; nt < 8; nt++) hv[nt] = (short)f2bf(acc[mf][nt][reg]);
                *reinterpret_cast<short8*>(&h[(size_t)m * F_OUT + l16 * 8]) = hv;
            }
        }
    }
}

// ---- bucket build: group edges by 64-row bucket (rl tag in bits 24-31) -----
__global__ __launch_bounds__(256) void bucket_hist(const int* __restrict__ row,
                                                   int* __restrict__ bucket_total,
                                                   int* __restrict__ blockbase) {
    __shared__ int hist[NB];
    const int t = threadIdx.x, blk = blockIdx.x;
    for (int i = t; i < NB; i += 256) hist[i] = 0;
    __syncthreads();
    const long tb = (long)blk * TILE;
    #pragma unroll
    for (int c = 0; c < 8; c++) {
        long i0 = tb + c * 1024 + t * 4;
        if (i0 + 4 <= N_EDGES) {
            int4 r = *reinterpret_cast<const int4*>(row + i0);
            atomicAdd(&hist[r.x >> 6], 1); atomicAdd(&hist[r.y >> 6], 1);
            atomicAdd(&hist[r.z >> 6], 1); atomicAdd(&hist[r.w >> 6], 1);
        } else {
            for (long i = i0; i < N_EDGES && i < i0 + 4; i++)
                atomicAdd(&hist[row[i] >> 6], 1);
        }
    }
    __syncthreads();
    for (int bin = t; bin < NB; bin += 256)
        blockbase[bin * NBLK + blk] = atomicAdd(&bucket_total[bin], hist[bin]);
}

// exclusive scan over NB bucket totals: single wave, shfl-based, no barriers
__global__ void bucket_scan(const int* __restrict__ bucket_total,
                            int* __restrict__ bucket_base) {
    const int lane = threadIdx.x;          // 64 threads = 1 wave
    int loc[25];
    int s = 0;
    #pragma unroll
    for (int k = 0; k < 25; k++) {
        int idx = lane * 25 + k;           // 64*25 = 1600 >= NB+1
        int v = (idx < NB) ? bucket_total[idx] : 0;
        loc[k] = s; s += v;                // exclusive within chunk
    }
    int run = s;
    #pragma unroll
    for (int off = 1; off < 64; off <<= 1) {
        int u = __shfl_up(run, off);
        if (lane >= off) run += u;
    }
    const int base = run - s;              // exclusive prefix of this chunk
    #pragma unroll
    for (int k = 0; k < 25; k++) {
        int idx = lane * 25 + k;
        if (idx <= NB) bucket_base[idx] = base + loc[k];
    }
}

// scatter edges to bucket-grouped metabuf; rank via LDS cursor (no G atomics)
__global__ __launch_bounds__(256) void bucket_scatter(const int* __restrict__ row,
                                                      const int* __restrict__ col,
                                                      const float* __restrict__ val,
                                                      const int* __restrict__ bucket_base,
                                                      const int* __restrict__ blockbase,
                                                      int2* __restrict__ metabuf) {
    __shared__ int sbase[NB];
    const int t = threadIdx.x, blk = blockIdx.x;
    for (int bin = t; bin < NB; bin += 256)
        sbase[bin] = bucket_base[bin] + blockbase[bin * NBLK + blk];
    __syncthreads();
    const long tb = (long)blk * TILE;
    #pragma unroll
    for (int c = 0; c < 8; c++) {
        long i0 = tb + c * 1024 + t * 4;
        if (i0 + 4 <= N_EDGES) {
            int4 r  = *reinterpret_cast<const int4*>(row + i0);
            int4 cc = *reinterpret_cast<const int4*>(col + i0);
            floatx4 vv = *reinterpret_cast<const floatx4*>(val + i0);
            int rr[4] = {r.x, r.y, r.z, r.w};
            int c4[4] = {cc.x, cc.y, cc.z, cc.w};
            float v4[4] = {vv[0], vv[1], vv[2], vv[3]};
            #pragma unroll
            for (int j = 0; j < 4; j++) {
                int bin = rr[j] >> 6, rl = rr[j] & 63;
                int pos = atomicAdd(&sbase[bin], 1);
                metabuf[pos] = make_int2(c4[j] | (rl << 24), __float_as_int(v4[j]));
            }
        } else {
            for (long i = i0; i < N_EDGES && i < i0 + 4; i++) {
                int rv = row[i];
                int bin = rv >> 6, rl = rv & 63;
                int pos = atomicAdd(&sbase[bin], 1);
                metabuf[pos] = make_int2(col[i] | (rl << 24), __float_as_int(val[i]));
            }
        }
    }
}

// ---- SpMM fused with in-LDS binning: one block per 64-row bucket -----------
// Phase 1: single global read of meta (staged to LDS raw[] while histing),
//          1-wave shfl scan over 64 bins, LDS->LDS permute into ord[].
// Phase 2: 32 groups x 16 lanes; group owns 2 rows; 4 edges in flight;
//          register accumulation (round-3 body: 32 VGPR, NO depth-2 pipeline
//          -- round-4 lesson: pipelining under the 64-VGPR launch-bounds cap
//          spills to scratch, +428 MB HBM writes). Grid 1563 blocks sustains
//          4 blocks/CU (round-3's 782 averaged only ~3).
__global__ __launch_bounds__(512, 8) void spmm_fused(const unsigned short* __restrict__ h,
                                                     const int* __restrict__ bucket_base,
                                                     const int2* __restrict__ meta,
                                                     const float* __restrict__ bias,
                                                     float* __restrict__ out) {
    __shared__ int2 raw[CAP];                      // 12 KB
    __shared__ int2 ord[CAP];                      // 12 KB
    __shared__ int hist[64], startS[64], cursor[64];
    const int t = threadIdx.x, b = blockIdx.x;
    const int b0 = bucket_base[b];
    int n = bucket_base[b + 1] - b0; if (n > CAP) n = CAP;

    if (t < 64) hist[t] = 0;
    __syncthreads();
    // single global pass: stage + histogram
    for (int i = t; i < n; i += 512) {
        int2 e = meta[b0 + i];
        raw[i] = e;
        atomicAdd(&hist[((unsigned)e.x >> 24) & 63], 1);
    }
    __syncthreads();
    // single-wave exclusive scan over 64 bins
    if (t < 64) {
        int h0 = hist[t];
        int s0 = h0;
        #pragma unroll
        for (int off = 1; off < 64; off <<= 1) {
            int u = __shfl_up(s0, off);
            if (t >= off) s0 += u;
        }
        startS[t] = s0 - h0; cursor[t] = s0 - h0;
    }
    __syncthreads();
    // LDS->LDS permute into row order (strip rl tag from col)
    for (int i = t; i < n; i += 512) {
        int2 e = raw[i];
        int rl = ((unsigned)e.x >> 24) & 63;
        int pos = atomicAdd(&cursor[rl], 1);
        ord[pos] = make_int2(e.x & 0x00FFFFFF, e.y);
    }
    __syncthreads();

    // phase 2: register accumulation over row runs (acc[j] = channel j*16+l16)
    const int lane = t & 63;
    const int l16 = lane & 15;
    const int grp = (t >> 6) * 4 + (lane >> 4);    // 0..31
    const unsigned short* hp = h + l16 * 8;

    #pragma unroll
    for (int j = 0; j < 2; j++) {
        const int rl = grp * 2 + j;
        const int s = startS[rl], d = hist[rl];
        float acc[8];
        #pragma unroll
        for (int k = 0; k < 8; k++) acc[k] = 0.f;
        for (int i = 0; i < d; i += 4) {
            int2 mm[4];
            #pragma unroll
            for (int u = 0; u < 4; u++) {
                int idx = i + u; if (idx > d - 1) idx = d - 1;
                mm[u] = ord[s + idx];
            }
            uint4 hv[4];
            #pragma unroll
            for (int u = 0; u < 4; u++)
                hv[u] = *reinterpret_cast<const uint4*>(hp + (size_t)mm[u].x * F_OUT);
            #pragma unroll
            for (int u = 0; u < 4; u++) {
                float v = (i + u < d) ? __int_as_float(mm[u].y) : 0.f;
                #pragma unroll
                for (int k = 0; k < 4; k++) {
                    unsigned uu = ((const unsigned*)&hv[u])[k];
                    acc[2 * k]     += v * __uint_as_float(uu << 16);
                    acc[2 * k + 1] += v * __uint_as_float(uu & 0xffff0000u);
                }
            }
        }
        const int r = b * 64 + rl;
        if (r < N_NODES) {
            float* op = out + (size_t)r * F_OUT + l16;
            #pragma unroll
            for (int jc = 0; jc < 8; jc++) {
                float o = fmaxf(acc[jc] + bias[jc * 16 + l16], 0.f);
                op[jc * 16] = o;                   // 16 lanes x 4 B = 64 B/instr
            }
        }
    }
}

extern "C" void kernel_launch(void* const* d_in, const int* in_sizes, int n_in,
                              void* d_out, int out_size, void* d_ws, size_t ws_size,
                              hipStream_t stream) {
    const float* x        = (const float*)d_in[0];
    const int*   adj_row  = (const int*)d_in[1];
    const int*   adj_col  = (const int*)d_in[2];
    const float* adj_vals = (const float*)d_in[3];
    const float* w        = (const float*)d_in[4];
    const float* b        = (const float*)d_in[5];
    float* out = (float*)d_out;

    // workspace layout (16B-aligned)
    char* ws = (char*)d_ws;
    unsigned short* wT = (unsigned short*)ws;                          // 64 KB
    unsigned short* h  = (unsigned short*)(ws + 65536);                // 25.6 MB
    size_t off = 65536 + (size_t)N_NODES * F_OUT * 2;                  // 25,665,536
    int2* metabuf  = (int2*)(ws + off);   off += (size_t)N_EDGES * 8;  // 12.8 MB
    int* blockbase = (int*)(ws + off);    off += (size_t)NB * NBLK * 4;
    int* bucket_total = (int*)(ws + off); off += 8192;
    int* bucket_base  = (int*)(ws + off); off += 8192;

    prep_w<<<128, 256, 0, stream>>>(w, wT);
    hipMemsetAsync(bucket_total, 0, NB * 4, stream);
    gemm_xw<<<(N_NODES + 255) / 256, 256, 0, stream>>>(x, wT, h);
    bucket_hist<<<NBLK, 256, 0, stream>>>(adj_row, bucket_total, blockbase);
    bucket_scan<<<1, 64, 0, stream>>>(bucket_total, bucket_base);
    bucket_scatter<<<NBLK, 256, 0, stream>>>(adj_row, adj_col, adj_vals,
                                             bucket_base, blockbase, metabuf);
    spmm_fused<<<NB, 512, 0, stream>>>(h, bucket_base, metabuf, b, out);
}

// Round 6
// 287.778 us; speedup vs baseline: 1.6233x; 1.0573x over previous
//
#include <hip/hip_runtime.h>
#include <hip/hip_bf16.h>
#include <cstdint>
#include <cstddef>

#define N_NODES 100000
#define N_EDGES 1600000
#define F_IN 256
#define F_OUT 128

#define NB 1563       // buckets = row >> 6 (64 rows each); 99999>>6 = 1562
#define NBLK 196      // tiles for the scatter half of fused_mid
#define TILE 8192     // edges per tile
#define CAP 1536      // fixed metabuf slots per bucket (mean 1024, +16 sigma)
#define GEMM_BLOCKS 391

typedef __attribute__((ext_vector_type(8))) short short8;
typedef __attribute__((ext_vector_type(4))) float floatx4;

static __device__ __forceinline__ unsigned short f2bf(float f) {
    union { float f; unsigned u; } v; v.f = f;
    unsigned r = v.u + 0x7FFF + ((v.u >> 16) & 1);   // RNE
    return (unsigned short)(r >> 16);
}

// ---- w prep + cnt zero: fp32 [256][128] -> bf16 swizzled wT ----------------
__global__ void prep_w(const float* __restrict__ w, unsigned short* __restrict__ wT,
                       int* __restrict__ cnt) {
    int i = blockIdx.x * 256 + threadIdx.x;   // 0..32767
    int k = i >> 7;
    int n = i & 127;
    int g = (k >> 3) ^ (n & 7);
    wT[n * 256 + g * 8 + (k & 7)] = f2bf(w[i]);
    if (blockIdx.x == 0)
        for (int j = threadIdx.x; j < NB; j += 256) cnt[j] = 0;
}

// ---- fused_mid: blocks [0,391) = GEMM, [391,587) = bucket scatter ----------
// GEMM: h[100000][128] (bf16, channel-permuted: position p holds channel
// (p&7)*16+(p>>3); lane l16's 16B then carries channels {j*16+l16}).
// Scatter (2-pass, fixed bucket regions -> no global scan kernel):
//   pass1 LDS hist over row; reserve atomicAdd(&cnt[bin], hist[bin]) once per
//   touched bin; pass2 re-read (L2-hot) row/col/val and write each edge at
//   bin*CAP + rank -> per-(block,bin) runs are contiguous (fewer 32B sectors).
__global__ __launch_bounds__(256, 2) void fused_mid(const float* __restrict__ x,
                                                    const unsigned short* __restrict__ wT,
                                                    unsigned short* __restrict__ h,
                                                    const int* __restrict__ row,
                                                    const int* __restrict__ col,
                                                    const float* __restrict__ val,
                                                    int* __restrict__ cnt,
                                                    int2* __restrict__ metabuf) {
    __shared__ __align__(16) unsigned short smem[128 * 256];   // 64 KB union
    const int tid = threadIdx.x;

    if (blockIdx.x < GEMM_BLOCKS) {
        unsigned short* wlds = smem;
        {
            const floatx4* src = reinterpret_cast<const floatx4*>(wT);
            floatx4* dst = reinterpret_cast<floatx4*>(wlds);
            #pragma unroll
            for (int i = 0; i < 16; i++) dst[tid + i * 256] = src[tid + i * 256];
        }
        __syncthreads();

        const int wave = tid >> 6, lane = tid & 63;
        const int quad = lane >> 4, l16 = lane & 15;
        const int rowbase = blockIdx.x * 256 + wave * 64;

        floatx4 acc[4][8];
        #pragma unroll
        for (int mf = 0; mf < 4; mf++)
            #pragma unroll
            for (int nt = 0; nt < 8; nt++) acc[mf][nt] = (floatx4)0.f;

        #pragma unroll
        for (int ks = 0; ks < 8; ks++) {
            const int k0 = ks * 32 + quad * 8;
            short8 afrag[4];
            #pragma unroll
            for (int mf = 0; mf < 4; mf++) {
                int r = rowbase + mf * 16 + l16;
                if (r >= N_NODES) r = N_NODES - 1;
                const float* xp = x + (size_t)r * F_IN + k0;
                floatx4 x0 = *reinterpret_cast<const floatx4*>(xp);
                floatx4 x1 = *reinterpret_cast<const floatx4*>(xp + 4);
                short8 a;
                a[0] = (short)f2bf(x0[0]); a[1] = (short)f2bf(x0[1]);
                a[2] = (short)f2bf(x0[2]); a[3] = (short)f2bf(x0[3]);
                a[4] = (short)f2bf(x1[0]); a[5] = (short)f2bf(x1[1]);
                a[6] = (short)f2bf(x1[2]); a[7] = (short)f2bf(x1[3]);
                afrag[mf] = a;
            }
            short8 bfrag[8];
            const int gq = ks * 4 + quad;
            #pragma unroll
            for (int nt = 0; nt < 8; nt++) {
                const int n = nt * 16 + l16;
                const int g = gq ^ (n & 7);
                bfrag[nt] = *reinterpret_cast<const short8*>(&wlds[n * 256 + g * 8]);
            }
            #pragma unroll
            for (int mf = 0; mf < 4; mf++)
                #pragma unroll
                for (int nt = 0; nt < 8; nt++)
                    acc[mf][nt] = __builtin_amdgcn_mfma_f32_16x16x32_bf16(
                        afrag[mf], bfrag[nt], acc[mf][nt], 0, 0, 0);
        }

        #pragma unroll
        for (int mf = 0; mf < 4; mf++) {
            const int mbase = rowbase + mf * 16 + quad * 4;
            #pragma unroll
            for (int reg = 0; reg < 4; reg++) {
                const int m = mbase + reg;
                if (m < N_NODES) {
                    short8 hv;
                    #pragma unroll
                    for (int nt = 0; nt < 8; nt++) hv[nt] = (short)f2bf(acc[mf][nt][reg]);
                    *reinterpret_cast<short8*>(&h[(size_t)m * F_OUT + l16 * 8]) = hv;
                }
            }
        }
    } else {
        // ---- scatter half ----
        int* hist   = reinterpret_cast<int*>(smem);        // NB ints
        int* cursor = hist + NB;                           // NB ints
        const int blk = blockIdx.x - GEMM_BLOCKS;
        for (int i = tid; i < NB; i += 256) hist[i] = 0;
        __syncthreads();
        const long tb = (long)blk * TILE;
        // pass 1: histogram over row
        #pragma unroll
        for (int c = 0; c < 8; c++) {
            long i0 = tb + c * 1024 + tid * 4;
            if (i0 + 4 <= N_EDGES) {
                int4 r = *reinterpret_cast<const int4*>(row + i0);
                atomicAdd(&hist[r.x >> 6], 1); atomicAdd(&hist[r.y >> 6], 1);
                atomicAdd(&hist[r.z >> 6], 1); atomicAdd(&hist[r.w >> 6], 1);
            } else {
                for (long i = i0; i < N_EDGES && i < i0 + 4; i++)
                    atomicAdd(&hist[row[i] >> 6], 1);
            }
        }
        __syncthreads();
        // reserve global ranges (one atomic per touched bin)
        for (int bin = tid; bin < NB; bin += 256) {
            int hc = hist[bin];
            int base = bin * CAP;
            if (hc) base += atomicAdd(&cnt[bin], hc);
            cursor[bin] = base;
        }
        __syncthreads();
        // pass 2: write edges (row re-read is L2-hot)
        #pragma unroll
        for (int c = 0; c < 8; c++) {
            long i0 = tb + c * 1024 + tid * 4;
            if (i0 + 4 <= N_EDGES) {
                int4 r  = *reinterpret_cast<const int4*>(row + i0);
                int4 cc = *reinterpret_cast<const int4*>(col + i0);
                floatx4 vv = *reinterpret_cast<const floatx4*>(val + i0);
                int rr[4] = {r.x, r.y, r.z, r.w};
                int c4[4] = {cc.x, cc.y, cc.z, cc.w};
                float v4[4] = {vv[0], vv[1], vv[2], vv[3]};
                #pragma unroll
                for (int j = 0; j < 4; j++) {
                    int bin = rr[j] >> 6, rl = rr[j] & 63;
                    int pos = atomicAdd(&cursor[bin], 1);
                    if (pos < (bin + 1) * CAP)
                        metabuf[pos] = make_int2(c4[j] | (rl << 24), __float_as_int(v4[j]));
                }
            } else {
                for (long i = i0; i < N_EDGES && i < i0 + 4; i++) {
                    int rv = row[i];
                    int bin = rv >> 6, rl = rv & 63;
                    int pos = atomicAdd(&cursor[bin], 1);
                    if (pos < (bin + 1) * CAP)
                        metabuf[pos] = make_int2(col[i] | (rl << 24), __float_as_int(val[i]));
                }
            }
        }
    }
}

// ---- SpMM fused with in-LDS binning: one block per 64-row bucket -----------
// Phase 1: single global read of meta (staged to LDS raw[] while histing),
//          1-wave shfl scan over 64 bins, LDS->LDS permute into ord[].
// Phase 2: 32 groups x 16 lanes; group owns 2 rows; 4 edges in flight;
//          register accumulation, 32 VGPR (no deeper pipeline: round-4 lesson
//          -- pipelining under the 64-VGPR launch-bounds cap spills to HBM).
__global__ __launch_bounds__(512, 8) void spmm_fused(const unsigned short* __restrict__ h,
                                                     const int* __restrict__ cnt,
                                                     const int2* __restrict__ meta,
                                                     const float* __restrict__ bias,
                                                     float* __restrict__ out) {
    __shared__ int2 raw[CAP];                      // 12 KB
    __shared__ int2 ord[CAP];                      // 12 KB
    __shared__ int hist[64], startS[64], cursor[64];
    const int t = threadIdx.x, b = blockIdx.x;
    const int b0 = b * CAP;
    int n = cnt[b]; if (n > CAP) n = CAP;

    if (t < 64) hist[t] = 0;
    __syncthreads();
    // single global pass: stage + histogram
    for (int i = t; i < n; i += 512) {
        int2 e = meta[b0 + i];
        raw[i] = e;
        atomicAdd(&hist[((unsigned)e.x >> 24) & 63], 1);
    }
    __syncthreads();
    // single-wave exclusive scan over 64 bins
    if (t < 64) {
        int h0 = hist[t];
        int s0 = h0;
        #pragma unroll
        for (int off = 1; off < 64; off <<= 1) {
            int u = __shfl_up(s0, off);
            if (t >= off) s0 += u;
        }
        startS[t] = s0 - h0; cursor[t] = s0 - h0;
    }
    __syncthreads();
    // LDS->LDS permute into row order (strip rl tag from col)
    for (int i = t; i < n; i += 512) {
        int2 e = raw[i];
        int rl = ((unsigned)e.x >> 24) & 63;
        int pos = atomicAdd(&cursor[rl], 1);
        ord[pos] = make_int2(e.x & 0x00FFFFFF, e.y);
    }
    __syncthreads();

    // phase 2: register accumulation over row runs (acc[j] = channel j*16+l16)
    const int lane = t & 63;
    const int l16 = lane & 15;
    const int grp = (t >> 6) * 4 + (lane >> 4);    // 0..31
    const unsigned short* hp = h + l16 * 8;

    #pragma unroll
    for (int j = 0; j < 2; j++) {
        const int rl = grp * 2 + j;
        const int s = startS[rl], d = hist[rl];
        float acc[8];
        #pragma unroll
        for (int k = 0; k < 8; k++) acc[k] = 0.f;
        for (int i = 0; i < d; i += 4) {
            int2 mm[4];
            #pragma unroll
            for (int u = 0; u < 4; u++) {
                int idx = i + u; if (idx > d - 1) idx = d - 1;
                mm[u] = ord[s + idx];
            }
            uint4 hv[4];
            #pragma unroll
            for (int u = 0; u < 4; u++)
                hv[u] = *reinterpret_cast<const uint4*>(hp + (size_t)mm[u].x * F_OUT);
            #pragma unroll
            for (int u = 0; u < 4; u++) {
                float v = (i + u < d) ? __int_as_float(mm[u].y) : 0.f;
                #pragma unroll
                for (int k = 0; k < 4; k++) {
                    unsigned uu = ((const unsigned*)&hv[u])[k];
                    acc[2 * k]     += v * __uint_as_float(uu << 16);
                    acc[2 * k + 1] += v * __uint_as_float(uu & 0xffff0000u);
                }
            }
        }
        const int r = b * 64 + rl;
        if (r < N_NODES) {
            float* op = out + (size_t)r * F_OUT + l16;
            #pragma unroll
            for (int jc = 0; jc < 8; jc++) {
                float o = fmaxf(acc[jc] + bias[jc * 16 + l16], 0.f);
                op[jc * 16] = o;                   // 16 lanes x 4 B = 64 B/instr
            }
        }
    }
}

extern "C" void kernel_launch(void* const* d_in, const int* in_sizes, int n_in,
                              void* d_out, int out_size, void* d_ws, size_t ws_size,
                              hipStream_t stream) {
    const float* x        = (const float*)d_in[0];
    const int*   adj_row  = (const int*)d_in[1];
    const int*   adj_col  = (const int*)d_in[2];
    const float* adj_vals = (const float*)d_in[3];
    const float* w        = (const float*)d_in[4];
    const float* b        = (const float*)d_in[5];
    float* out = (float*)d_out;

    // workspace layout (16B-aligned)
    char* ws = (char*)d_ws;
    unsigned short* wT = (unsigned short*)ws;                          // 64 KB
    unsigned short* h  = (unsigned short*)(ws + 65536);                // 25.6 MB
    size_t off = 65536 + (size_t)N_NODES * F_OUT * 2;                  // 25,665,536
    int2* metabuf = (int2*)(ws + off);  off += (size_t)NB * CAP * 8;   // 19.2 MB
    int* cnt      = (int*)(ws + off);   off += 8192;

    prep_w<<<128, 256, 0, stream>>>(w, wT, cnt);
    fused_mid<<<GEMM_BLOCKS + NBLK, 256, 0, stream>>>(x, wT, h, adj_row, adj_col,
                                                      adj_vals, cnt, metabuf);
    spmm_fused<<<NB, 512, 0, stream>>>(h, cnt, metabuf, b, out);
}